// Round 1
// baseline (191.787 us; speedup 1.0000x reference)
//
#include <hip/hip_runtime.h>
#include <math.h>

// Problem constants
#define BB 16
#define EE 512
#define HH 512
#define VV 32000
#define LL 512
#define NQ 20
#define H2 1024   // 2H
#define H3 1536   // 3H
#define H4 2048   // 4H

// Workspace layout (float offsets)
#define H0_OFF   0        // B*H      = 8192
#define GI_OFF   8192     // B*3H     = 24576
#define GH_OFF   32768    // B*3H     = 24576
#define H_OFF    57344    // B*H      = 8192
#define UQ_OFF   65536    // B*2H     = 16384
#define WHD_OFF  81920    // B        = 16
#define ED_OFF   81936    // B        = 16
#define SC_OFF   81952    // B*L      = 8192
#define QC_OFF   90144    // B*L      = 8192
#define PW_OFF   98336    // B*L      = 8192
// total = 106528 floats = 426 KB

__device__ __forceinline__ float wave_reduce_add(float v) {
#pragma unroll
  for (int off = 32; off > 0; off >>= 1) v += __shfl_xor(v, off, 64);
  return v;
}

// K1: h0[b,j] = concat([qn_t, g_t]) . fc_w[j,:] + fc_b[j]   (B*H waves)
//     gi[b,j] = embed[y[b]] . w_ih[j,:] + b_ih[j]           (B*3H waves)
__global__ __launch_bounds__(256) void k_h0_gi(
    const int* __restrict__ y, const float* __restrict__ qn, const float* __restrict__ g,
    const float* __restrict__ embed, const float* __restrict__ fc_w, const float* __restrict__ fc_b,
    const float* __restrict__ w_ih, const float* __restrict__ b_ih,
    float* __restrict__ h0_ws, float* __restrict__ gi_ws) {
  int gw = (blockIdx.x * 256 + threadIdx.x) >> 6;
  int lane = threadIdx.x & 63;
  if (gw < BB * HH) {
    int b = gw >> 9, j = gw & (HH - 1);
    const float4* fw  = (const float4*)(fc_w + (size_t)j * H4);
    const float4* qn4 = (const float4*)(qn + (size_t)b * (NQ * H2));
    const float4* g4  = (const float4*)(g  + (size_t)b * (NQ * H2));
    float acc = 0.f;
#pragma unroll
    for (int it = 0; it < 8; ++it) {
      int i4 = it * 64 + lane;                       // float4 idx 0..511
      float4 a = (i4 < 256) ? qn4[i4] : g4[i4 - 256];
      float4 w4 = fw[i4];
      acc += a.x * w4.x + a.y * w4.y + a.z * w4.z + a.w * w4.w;
    }
    acc = wave_reduce_add(acc);
    if (lane == 0) h0_ws[gw] = acc + fc_b[j];
  } else {
    int w2 = gw - BB * HH;
    int b = w2 / H3, j = w2 - b * H3;
    const float4* xr = (const float4*)(embed + (size_t)y[b] * EE);
    const float4* wr = (const float4*)(w_ih + (size_t)j * EE);
    float acc = 0.f;
#pragma unroll
    for (int it = 0; it < 2; ++it) {
      int i4 = it * 64 + lane;
      float4 a = xr[i4], w4 = wr[i4];
      acc += a.x * w4.x + a.y * w4.y + a.z * w4.z + a.w * w4.w;
    }
    acc = wave_reduce_add(acc);
    if (lane == 0) gi_ws[w2] = acc + b_ih[j];
  }
}

// K2: gh[b,j] = h0[b,:] . w_hh[j,:] + b_hh[j]   (B*3H waves)
__global__ __launch_bounds__(256) void k_gh(
    const float* __restrict__ h0_ws, const float* __restrict__ w_hh,
    const float* __restrict__ b_hh, float* __restrict__ gh_ws) {
  int gw = (blockIdx.x * 256 + threadIdx.x) >> 6;
  int lane = threadIdx.x & 63;
  int b = gw / H3, j = gw - b * H3;
  const float4* hr = (const float4*)(h0_ws + b * HH);
  const float4* wr = (const float4*)(w_hh + (size_t)j * HH);
  float acc = 0.f;
#pragma unroll
  for (int it = 0; it < 2; ++it) {
    int i4 = it * 64 + lane;
    float4 a = hr[i4], w4 = wr[i4];
    acc += a.x * w4.x + a.y * w4.y + a.z * w4.z + a.w * w4.w;
  }
  acc = wave_reduce_add(acc);
  if (lane == 0) gh_ws[gw] = acc + b_hh[j];
}

// K3: GRU elementwise -> h;  wh_dot[b] = h.wh_w;  e_dot[b] = embed[y[b]].wy_w
__global__ __launch_bounds__(512) void k_gru(
    const int* __restrict__ y, const float* __restrict__ embed,
    const float* __restrict__ gi_ws, const float* __restrict__ gh_ws,
    const float* __restrict__ h0_ws,
    const float* __restrict__ wh_w, const float* __restrict__ wy_w,
    float* __restrict__ h_ws, float* __restrict__ whd_ws, float* __restrict__ ed_ws) {
  int b = blockIdx.x, j = threadIdx.x;
  const float* gi = gi_ws + b * H3;
  const float* gh = gh_ws + b * H3;
  float r = 1.f / (1.f + expf(-(gi[j] + gh[j])));
  float z = 1.f / (1.f + expf(-(gi[HH + j] + gh[HH + j])));
  float n = tanhf(gi[2 * HH + j] + r * gh[2 * HH + j]);
  float h0v = h0_ws[b * HH + j];
  float hv = (1.f - z) * n + z * h0v;
  h_ws[b * HH + j] = hv;
  float p1 = hv * wh_w[j];
  float p2 = embed[(size_t)y[b] * EE + j] * wy_w[j];
  p1 = wave_reduce_add(p1);
  p2 = wave_reduce_add(p2);
  __shared__ float red1[8], red2[8];
  int wid = j >> 6, lane = j & 63;
  if (lane == 0) { red1[wid] = p1; red2[wid] = p2; }
  __syncthreads();
  if (j == 0) {
    float s1 = 0.f, s2 = 0.f;
#pragma unroll
    for (int i = 0; i < 8; ++i) { s1 += red1[i]; s2 += red2[i]; }
    whd_ws[b] = s1;
    ed_ws[b] = s2;
  }
}

// K4: u_q[b,d] = sum_h h[b,h] * w_la[h, d]   (w_la row-major (H, 2H))
__global__ __launch_bounds__(256) void k_uq(
    const float* __restrict__ h_ws, const float* __restrict__ w_la,
    float* __restrict__ uq_ws) {
  int idx = blockIdx.x * 256 + threadIdx.x;
  int b = idx >> 10, d = idx & (H2 - 1);
  const float* hr = h_ws + b * HH;
  float acc = 0.f;
#pragma unroll 4
  for (int k = 0; k < HH; ++k) acc += hr[k] * w_la[k * H2 + d];
  uq_ws[idx] = acc;
}

// K5: score[b,l] = u_q[b,:] . q_t[b,l,:];  qc[b,l] = q_t[b,l,:] . wc_w
__global__ __launch_bounds__(256) void k_score(
    const float* __restrict__ q, const float* __restrict__ uq_ws,
    const float* __restrict__ wc_w,
    float* __restrict__ score_ws, float* __restrict__ qc_ws) {
  int gw = (blockIdx.x * 256 + threadIdx.x) >> 6;
  int lane = threadIdx.x & 63;
  int b = gw >> 9, l = gw & (LL - 1);
  const float4* qr = (const float4*)(q + (size_t)b * NQ * LL * H2 + (size_t)l * H2);
  const float4* ur = (const float4*)(uq_ws + b * H2);
  const float4* wr = (const float4*)wc_w;
  float a1 = 0.f, a2 = 0.f;
#pragma unroll
  for (int it = 0; it < 4; ++it) {
    int i4 = it * 64 + lane;
    float4 qv = qr[i4], uv = ur[i4], wv = wr[i4];
    a1 += qv.x * uv.x + qv.y * uv.y + qv.z * uv.z + qv.w * uv.w;
    a2 += qv.x * wv.x + qv.y * wv.y + qv.z * wv.z + qv.w * wv.w;
  }
  a1 = wave_reduce_add(a1);
  a2 = wave_reduce_add(a2);
  if (lane == 0) { score_ws[gw] = a1; qc_ws[gw] = a2; }
}

// K6: softmax over l; c_dot; p_gen; P_w = p_gen + beta*(1-p_gen)
__global__ __launch_bounds__(512) void k_softmax(
    const float* __restrict__ score_ws, const float* __restrict__ qc_ws,
    const float* __restrict__ whd_ws, const float* __restrict__ ed_ws,
    float* __restrict__ pw_ws) {
  int b = blockIdx.x, l = threadIdx.x;
  float s = score_ws[b * LL + l];
  float qc = qc_ws[b * LL + l];
  __shared__ float redm[8], red_e[8], red_q[8];
  int wid = l >> 6, lane = l & 63;
  float m = s;
#pragma unroll
  for (int off = 32; off > 0; off >>= 1) m = fmaxf(m, __shfl_xor(m, off, 64));
  if (lane == 0) redm[wid] = m;
  __syncthreads();
  float mm = redm[0];
#pragma unroll
  for (int i = 1; i < 8; ++i) mm = fmaxf(mm, redm[i]);
  float e = expf(s - mm);
  float se = wave_reduce_add(e);
  float sq = wave_reduce_add(e * qc);
  if (lane == 0) { red_e[wid] = se; red_q[wid] = sq; }
  __syncthreads();
  float Se = 0.f, Sq = 0.f;
#pragma unroll
  for (int i = 0; i < 8; ++i) { Se += red_e[i]; Sq += red_q[i]; }
  float inv = 1.f / Se;
  float c_dot = Sq * inv;
  float p = whd_ws[b] + c_dot + ed_ws[b];
  float pg = p > 0.f ? p : 0.2f * p;
  pw_ws[b * LL + l] = pg + (e * inv) * (1.f - pg);
}

// K7: pre[b,v] = P_w[b,:] . fco_w[v,:] + fco_b[v]
// block = 256 threads = 16 v x 16 b; P_w staged in LDS with pad (stride 516)
__global__ __launch_bounds__(256) void k_final(
    const float* __restrict__ pw_ws, const float* __restrict__ fco_w,
    const float* __restrict__ fco_b, float* __restrict__ out) {
  __shared__ float plds[16 * 516];
  int tid = threadIdx.x;
#pragma unroll
  for (int it = 0; it < 8; ++it) {
    int i4 = it * 256 + tid;        // float4 index over 2048
    int row = i4 >> 7;              // / (512/4)
    int col = (i4 & 127) * 4;
    float4 v = ((const float4*)pw_ws)[i4];
    *(float4*)&plds[row * 516 + col] = v;
  }
  __syncthreads();
  int v = blockIdx.x * 16 + (tid & 15);
  int b = tid >> 4;
  const float4* fr = (const float4*)(fco_w + (size_t)v * LL);
  const float4* pr = (const float4*)&plds[b * 516];
  float acc = 0.f;
#pragma unroll 8
  for (int k4 = 0; k4 < 128; ++k4) {
    float4 f = fr[k4];
    float4 p = pr[k4];
    acc += f.x * p.x + f.y * p.y + f.z * p.z + f.w * p.w;
  }
  out[(size_t)b * VV + v] = acc + fco_b[v];
}

extern "C" void kernel_launch(void* const* d_in, const int* in_sizes, int n_in,
                              void* d_out, int out_size, void* d_ws, size_t ws_size,
                              hipStream_t stream) {
  const int*   y     = (const int*)d_in[0];
  const float* q     = (const float*)d_in[1];
  const float* qn    = (const float*)d_in[2];
  const float* g     = (const float*)d_in[3];
  const float* embed = (const float*)d_in[4];
  const float* fc_w  = (const float*)d_in[5];
  const float* fc_b  = (const float*)d_in[6];
  const float* w_ih  = (const float*)d_in[7];
  const float* w_hh  = (const float*)d_in[8];
  const float* b_ih  = (const float*)d_in[9];
  const float* b_hh  = (const float*)d_in[10];
  // d_in[11] w_ga, d_in[13] wv_w, d_in[14] wv_b are dead (P_vocab == 1)
  const float* w_la  = (const float*)d_in[12];
  const float* wh_w  = (const float*)d_in[15];
  const float* wc_w  = (const float*)d_in[16];
  const float* wy_w  = (const float*)d_in[17];
  const float* fco_w = (const float*)d_in[18];
  const float* fco_b = (const float*)d_in[19];
  float* ws  = (float*)d_ws;
  float* out = (float*)d_out;

  // waves: B*H (h0) + B*3H (gi) = 32768 -> 8192 blocks of 4 waves
  k_h0_gi<<<8192, 256, 0, stream>>>(y, qn, g, embed, fc_w, fc_b, w_ih, b_ih,
                                    ws + H0_OFF, ws + GI_OFF);
  // waves: B*3H = 24576 -> 6144 blocks
  k_gh<<<6144, 256, 0, stream>>>(ws + H0_OFF, w_hh, b_hh, ws + GH_OFF);
  k_gru<<<BB, 512, 0, stream>>>(y, embed, ws + GI_OFF, ws + GH_OFF, ws + H0_OFF,
                                wh_w, wy_w, ws + H_OFF, ws + WHD_OFF, ws + ED_OFF);
  // B*2H outputs / 256 = 64 blocks
  k_uq<<<64, 256, 0, stream>>>(ws + H_OFF, w_la, ws + UQ_OFF);
  // waves: B*L = 8192 -> 2048 blocks
  k_score<<<2048, 256, 0, stream>>>(q, ws + UQ_OFF, wc_w, ws + SC_OFF, ws + QC_OFF);
  k_softmax<<<BB, 512, 0, stream>>>(ws + SC_OFF, ws + QC_OFF, ws + WHD_OFF,
                                    ws + ED_OFF, ws + PW_OFF);
  // V / 16 = 2000 blocks
  k_final<<<2000, 256, 0, stream>>>(ws + PW_OFF, fco_w, fco_b, out);
}

// Round 2
// 165.359 us; speedup vs baseline: 1.1598x; 1.1598x over previous
//
#include <hip/hip_runtime.h>
#include <math.h>

// Problem constants
#define BB 16
#define EE 512
#define HH 512
#define VV 32000
#define LL 512
#define NQ 20
#define H2 1024   // 2H
#define H3 1536   // 3H
#define H4 2048   // 4H

// Workspace layout (float offsets)
#define H0_OFF   0        // B*H      = 8192
#define GI_OFF   8192     // B*3H     = 24576
#define GH_OFF   32768    // B*3H     = 24576
#define H_OFF    57344    // B*H      = 8192
#define UQ_OFF   65536    // B*2H     = 16384
#define WHD_OFF  81920    // B        = 16
#define ED_OFF   81936    // B        = 16
#define SC_OFF   81952    // B*L      = 8192
#define QC_OFF   90144    // B*L      = 8192
#define PW_OFF   98336    // B*L      = 8192

__device__ __forceinline__ float wave_reduce_add(float v) {
#pragma unroll
  for (int off = 32; off > 0; off >>= 1) v += __shfl_xor(v, off, 64);
  return v;
}

// K1: wave per output column j; loop over all 16 b in registers.
//   waves [0,512):    h0[b,j] = concat([qn_t,g_t][b]) . fc_w[j,:] + fc_b[j]
//   waves [512,2048): gi[b,j'] = embed[y[b]] . w_ih[j',:] + b_ih[j']
// Weights read from HBM exactly once; activations (128KB) L1/L2-resident.
__global__ __launch_bounds__(256) void k_in_gemm(
    const int* __restrict__ y, const float* __restrict__ qn, const float* __restrict__ g,
    const float* __restrict__ embed,
    const float* __restrict__ fc_w, const float* __restrict__ fc_b,
    const float* __restrict__ w_ih, const float* __restrict__ b_ih,
    float* __restrict__ h0_ws, float* __restrict__ gi_ws) {
  int gw = (blockIdx.x * 256 + threadIdx.x) >> 6;   // 0..2047
  int lane = threadIdx.x & 63;
  if (gw < HH) {
    int j = gw;
    const float4* fw = (const float4*)(fc_w + (size_t)j * H4);
    float4 w[8];
#pragma unroll
    for (int it = 0; it < 8; ++it) w[it] = fw[it * 64 + lane];
    float acc[16];
#pragma unroll
    for (int b = 0; b < 16; ++b) {
      const float4* qn4 = (const float4*)(qn + (size_t)b * (NQ * H2));
      const float4* g4  = (const float4*)(g  + (size_t)b * (NQ * H2));
      float a = 0.f;
#pragma unroll
      for (int it = 0; it < 8; ++it) {
        int i4 = it * 64 + lane;
        float4 av = (i4 < 256) ? qn4[i4] : g4[i4 - 256];
        a += av.x * w[it].x + av.y * w[it].y + av.z * w[it].z + av.w * w[it].w;
      }
      acc[b] = a;
    }
#pragma unroll
    for (int b = 0; b < 16; ++b) {
      float s = wave_reduce_add(acc[b]);
      if (lane == b) h0_ws[b * HH + j] = s + fc_b[j];
    }
  } else {
    int j = gw - HH;   // 0..1535
    const float4* wr = (const float4*)(w_ih + (size_t)j * EE);
    float4 w0 = wr[lane], w1 = wr[64 + lane];
    float acc[16];
#pragma unroll
    for (int b = 0; b < 16; ++b) {
      const float4* xr = (const float4*)(embed + (size_t)y[b] * EE);
      float4 a0 = xr[lane], a1 = xr[64 + lane];
      acc[b] = a0.x * w0.x + a0.y * w0.y + a0.z * w0.z + a0.w * w0.w
             + a1.x * w1.x + a1.y * w1.y + a1.z * w1.z + a1.w * w1.w;
    }
#pragma unroll
    for (int b = 0; b < 16; ++b) {
      float s = wave_reduce_add(acc[b]);
      if (lane == b) gi_ws[b * H3 + j] = s + b_ih[j];
    }
  }
}

// K2: wave per column j of w_hh; loop over b. gh[b,j] = h0[b,:] . w_hh[j,:] + b_hh[j]
__global__ __launch_bounds__(256) void k_gh(
    const float* __restrict__ h0_ws, const float* __restrict__ w_hh,
    const float* __restrict__ b_hh, float* __restrict__ gh_ws) {
  int gw = (blockIdx.x * 256 + threadIdx.x) >> 6;   // 0..1535
  int lane = threadIdx.x & 63;
  int j = gw;
  const float4* wr = (const float4*)(w_hh + (size_t)j * HH);
  float4 w0 = wr[lane], w1 = wr[64 + lane];
  float acc[16];
#pragma unroll
  for (int b = 0; b < 16; ++b) {
    const float4* hr = (const float4*)(h0_ws + b * HH);
    float4 a0 = hr[lane], a1 = hr[64 + lane];
    acc[b] = a0.x * w0.x + a0.y * w0.y + a0.z * w0.z + a0.w * w0.w
           + a1.x * w1.x + a1.y * w1.y + a1.z * w1.z + a1.w * w1.w;
  }
#pragma unroll
  for (int b = 0; b < 16; ++b) {
    float s = wave_reduce_add(acc[b]);
    if (lane == b) gh_ws[b * H3 + j] = s + b_hh[j];
  }
}

// K3: GRU elementwise -> h;  whd[b] = h.wh_w;  ed[b] = embed[y[b]].wy_w
__global__ __launch_bounds__(512) void k_gru(
    const int* __restrict__ y, const float* __restrict__ embed,
    const float* __restrict__ gi_ws, const float* __restrict__ gh_ws,
    const float* __restrict__ h0_ws,
    const float* __restrict__ wh_w, const float* __restrict__ wy_w,
    float* __restrict__ h_ws, float* __restrict__ whd_ws, float* __restrict__ ed_ws) {
  int b = blockIdx.x, j = threadIdx.x;
  const float* gi = gi_ws + b * H3;
  const float* gh = gh_ws + b * H3;
  float r = 1.f / (1.f + expf(-(gi[j] + gh[j])));
  float z = 1.f / (1.f + expf(-(gi[HH + j] + gh[HH + j])));
  float n = tanhf(gi[2 * HH + j] + r * gh[2 * HH + j]);
  float h0v = h0_ws[b * HH + j];
  float hv = (1.f - z) * n + z * h0v;
  h_ws[b * HH + j] = hv;
  float p1 = wave_reduce_add(hv * wh_w[j]);
  float p2 = wave_reduce_add(embed[(size_t)y[b] * EE + j] * wy_w[j]);
  __shared__ float red1[8], red2[8];
  int wid = j >> 6, lane = j & 63;
  if (lane == 0) { red1[wid] = p1; red2[wid] = p2; }
  __syncthreads();
  if (j == 0) {
    float s1 = 0.f, s2 = 0.f;
#pragma unroll
    for (int i = 0; i < 8; ++i) { s1 += red1[i]; s2 += red2[i]; }
    whd_ws[b] = s1;
    ed_ws[b] = s2;
  }
}

// K4: u_q[b,d] = sum_k h[b,k] * w_la[k,d]. Block = (b, 64-d tile), 4-way K-split.
__global__ __launch_bounds__(256) void k_uq(
    const float* __restrict__ h_ws, const float* __restrict__ w_la,
    float* __restrict__ uq_ws) {
  int b = blockIdx.x >> 4;
  int dt = blockIdx.x & 15;
  int dl = threadIdx.x & 63;
  int ks = threadIdx.x >> 6;              // 0..3
  const float* hr = h_ws + b * HH + ks * 128;
  const float* wp = w_la + (size_t)(ks * 128) * H2 + dt * 64 + dl;
  float acc = 0.f;
#pragma unroll 8
  for (int k = 0; k < 128; ++k) acc += hr[k] * wp[(size_t)k * H2];
  __shared__ float red[4][64];
  red[ks][dl] = acc;
  __syncthreads();
  if (threadIdx.x < 64) {
    float s = red[0][threadIdx.x] + red[1][threadIdx.x]
            + red[2][threadIdx.x] + red[3][threadIdx.x];
    uq_ws[b * H2 + dt * 64 + threadIdx.x] = s;
  }
}

// K5: score[b,l] = u_q[b,:] . q_t[b,l,:];  qc[b,l] = q_t[b,l,:] . wc_w
__global__ __launch_bounds__(256) void k_score(
    const float* __restrict__ q, const float* __restrict__ uq_ws,
    const float* __restrict__ wc_w,
    float* __restrict__ score_ws, float* __restrict__ qc_ws) {
  int gw = (blockIdx.x * 256 + threadIdx.x) >> 6;
  int lane = threadIdx.x & 63;
  int b = gw >> 9, l = gw & (LL - 1);
  const float4* qr = (const float4*)(q + (size_t)b * NQ * LL * H2 + (size_t)l * H2);
  const float4* ur = (const float4*)(uq_ws + b * H2);
  const float4* wr = (const float4*)wc_w;
  float a1 = 0.f, a2 = 0.f;
#pragma unroll
  for (int it = 0; it < 4; ++it) {
    int i4 = it * 64 + lane;
    float4 qv = qr[i4], uv = ur[i4], wv = wr[i4];
    a1 += qv.x * uv.x + qv.y * uv.y + qv.z * uv.z + qv.w * uv.w;
    a2 += qv.x * wv.x + qv.y * wv.y + qv.z * wv.z + qv.w * wv.w;
  }
  a1 = wave_reduce_add(a1);
  a2 = wave_reduce_add(a2);
  if (lane == 0) { score_ws[gw] = a1; qc_ws[gw] = a2; }
}

// K6: softmax over l; c_dot; p_gen; P_w = p_gen + beta*(1-p_gen)
__global__ __launch_bounds__(512) void k_softmax(
    const float* __restrict__ score_ws, const float* __restrict__ qc_ws,
    const float* __restrict__ whd_ws, const float* __restrict__ ed_ws,
    float* __restrict__ pw_ws) {
  int b = blockIdx.x, l = threadIdx.x;
  float s = score_ws[b * LL + l];
  float qc = qc_ws[b * LL + l];
  __shared__ float redm[8], red_e[8], red_q[8];
  int wid = l >> 6, lane = l & 63;
  float m = s;
#pragma unroll
  for (int off = 32; off > 0; off >>= 1) m = fmaxf(m, __shfl_xor(m, off, 64));
  if (lane == 0) redm[wid] = m;
  __syncthreads();
  float mm = redm[0];
#pragma unroll
  for (int i = 1; i < 8; ++i) mm = fmaxf(mm, redm[i]);
  float e = expf(s - mm);
  float se = wave_reduce_add(e);
  float sq = wave_reduce_add(e * qc);
  if (lane == 0) { red_e[wid] = se; red_q[wid] = sq; }
  __syncthreads();
  float Se = 0.f, Sq = 0.f;
#pragma unroll
  for (int i = 0; i < 8; ++i) { Se += red_e[i]; Sq += red_q[i]; }
  float inv = 1.f / Se;
  float c_dot = Sq * inv;
  float p = whd_ws[b] + c_dot + ed_ws[b];
  float pg = p > 0.f ? p : 0.2f * p;
  pw_ws[b * LL + l] = pg + (e * inv) * (1.f - pg);
}

// K7: pre[b,v] = P_w[b,:] . fco_w[v,:] + fco_b[v]
__global__ __launch_bounds__(256) void k_final(
    const float* __restrict__ pw_ws, const float* __restrict__ fco_w,
    const float* __restrict__ fco_b, float* __restrict__ out) {
  __shared__ float plds[16 * 516];
  int tid = threadIdx.x;
#pragma unroll
  for (int it = 0; it < 8; ++it) {
    int i4 = it * 256 + tid;
    int row = i4 >> 7;
    int col = (i4 & 127) * 4;
    float4 v = ((const float4*)pw_ws)[i4];
    *(float4*)&plds[row * 516 + col] = v;
  }
  __syncthreads();
  int v = blockIdx.x * 16 + (tid & 15);
  int b = tid >> 4;
  const float4* fr = (const float4*)(fco_w + (size_t)v * LL);
  const float4* pr = (const float4*)&plds[b * 516];
  float acc = 0.f;
#pragma unroll 8
  for (int k4 = 0; k4 < 128; ++k4) {
    float4 f = fr[k4];
    float4 p = pr[k4];
    acc += f.x * p.x + f.y * p.y + f.z * p.z + f.w * p.w;
  }
  out[(size_t)b * VV + v] = acc + fco_b[v];
}

extern "C" void kernel_launch(void* const* d_in, const int* in_sizes, int n_in,
                              void* d_out, int out_size, void* d_ws, size_t ws_size,
                              hipStream_t stream) {
  const int*   y     = (const int*)d_in[0];
  const float* q     = (const float*)d_in[1];
  const float* qn    = (const float*)d_in[2];
  const float* g     = (const float*)d_in[3];
  const float* embed = (const float*)d_in[4];
  const float* fc_w  = (const float*)d_in[5];
  const float* fc_b  = (const float*)d_in[6];
  const float* w_ih  = (const float*)d_in[7];
  const float* w_hh  = (const float*)d_in[8];
  const float* b_ih  = (const float*)d_in[9];
  const float* b_hh  = (const float*)d_in[10];
  const float* w_la  = (const float*)d_in[12];
  const float* wh_w  = (const float*)d_in[15];
  const float* wc_w  = (const float*)d_in[16];
  const float* wy_w  = (const float*)d_in[17];
  const float* fco_w = (const float*)d_in[18];
  const float* fco_b = (const float*)d_in[19];
  float* ws  = (float*)d_ws;
  float* out = (float*)d_out;

  // 2048 waves (512 h0 + 1536 gi) -> 512 blocks
  k_in_gemm<<<512, 256, 0, stream>>>(y, qn, g, embed, fc_w, fc_b, w_ih, b_ih,
                                     ws + H0_OFF, ws + GI_OFF);
  // 1536 waves -> 384 blocks
  k_gh<<<384, 256, 0, stream>>>(ws + H0_OFF, w_hh, b_hh, ws + GH_OFF);
  k_gru<<<BB, 512, 0, stream>>>(y, embed, ws + GI_OFF, ws + GH_OFF, ws + H0_OFF,
                                wh_w, wy_w, ws + H_OFF, ws + WHD_OFF, ws + ED_OFF);
  // 16 b x 16 d-tiles = 256 blocks
  k_uq<<<256, 256, 0, stream>>>(ws + H_OFF, w_la, ws + UQ_OFF);
  // B*L waves = 8192 -> 2048 blocks
  k_score<<<2048, 256, 0, stream>>>(q, ws + UQ_OFF, wc_w, ws + SC_OFF, ws + QC_OFF);
  k_softmax<<<BB, 512, 0, stream>>>(ws + SC_OFF, ws + QC_OFF, ws + WHD_OFF,
                                    ws + ED_OFF, ws + PW_OFF);
  k_final<<<2000, 256, 0, stream>>>(ws + PW_OFF, fco_w, fco_b, out);
}